// Round 3
// baseline (539.194 us; speedup 1.0000x reference)
//
#include <hip/hip_runtime.h>
#include <hip/hip_bf16.h>
#include <stdint.h>

// Problem constants (fixed by the reference)
#define N_NODES 50000
#define E_EDGES 640000
#define NB_TILES 782           // ceil(50000/64)
#define NKEY 400000            // N_NODES * R
#define NKEYP 400384           // 391 * 1024 (scan-padded)
#define SCAN_BLOCKS 391

typedef __attribute__((ext_vector_type(8))) short short8;   // 8 bf16 (MFMA A/B frag)
typedef __attribute__((ext_vector_type(4))) float float4v;  // MFMA C/D frag

__device__ __forceinline__ unsigned short f32_to_bf16(float f) {
  uint32_t u = __float_as_uint(f);
  u += 0x7fffu + ((u >> 16) & 1u);          // round-to-nearest-even
  return (unsigned short)(u >> 16);
}

// ---------------------------------------------------------------------------
// kx: convert x (f32) to bf16 row-array xb[N][128] once; all later consumers
// (edge gather + w1 GEMM) read the same rounded values.
// ---------------------------------------------------------------------------
__global__ __launch_bounds__(256) void kx_cvt(
    const float* __restrict__ x, unsigned short* __restrict__ xb) {
  int idx = blockIdx.x * 256 + threadIdx.x;       // 1.6M float4 groups
  float4 v = ((const float4*)x)[idx];
  uint32_t p0 = (uint32_t)f32_to_bf16(v.x) | ((uint32_t)f32_to_bf16(v.y) << 16);
  uint32_t p1 = (uint32_t)f32_to_bf16(v.z) | ((uint32_t)f32_to_bf16(v.w) << 16);
  ((uint2*)xb)[idx] = make_uint2(p0, p1);
}

// ---------------------------------------------------------------------------
// K0: transpose + convert the 11 [128][128] f32 weight matrices into a bf16
// bank wTg[m][o][k] (k-fast). m: 0..7 = W_rel[r], 8 = w1_W, 9 = m1_W, 10 = m2_W.
// ---------------------------------------------------------------------------
__global__ __launch_bounds__(256) void k0_tw(
    const float* __restrict__ W_rel, const float* __restrict__ w1W,
    const float* __restrict__ m1W, const float* __restrict__ m2W,
    unsigned short* __restrict__ wTg) {
  int m = blockIdx.x;
  const float* srcp = (m < 8) ? (W_rel + (size_t)m * 16384)
                              : (m == 8 ? w1W : (m == 9 ? m1W : m2W));
  unsigned short* dstp = wTg + (size_t)m * 16384;
  int tid = threadIdx.x;
  for (int i = 0; i < 64; ++i) {
    int idx = tid + i * 256;          // output flat index o*128 + k
    int o = idx >> 7, k = idx & 127;
    dstp[idx] = f32_to_bf16(srcp[k * 128 + o]);
  }
}

// ---------------------------------------------------------------------------
// CSR build: histogram by key = dst*8 + etype, exclusive scan, fill.
// k_fill bumps off[key] itself; afterwards off[key] = span END, and the span
// start is off[key] - cnt[key]  (no separate `cur` array).
// ---------------------------------------------------------------------------
__global__ __launch_bounds__(256) void k_hist(
    const int* __restrict__ dst, const int* __restrict__ ety, int* __restrict__ cnt) {
  int e = blockIdx.x * 256 + threadIdx.x;
  if (e < E_EDGES) atomicAdd(&cnt[dst[e] * 8 + ety[e]], 1);
}

__global__ __launch_bounds__(1024) void k_scanA(
    const int* __restrict__ cnt, int* __restrict__ off, int* __restrict__ btot) {
  __shared__ int s[1024];
  int t = threadIdx.x, g = blockIdx.x * 1024 + t;
  int v = cnt[g];
  s[t] = v; __syncthreads();
  for (int d = 1; d < 1024; d <<= 1) {
    int a = (t >= d) ? s[t - d] : 0;
    __syncthreads();
    s[t] += a;
    __syncthreads();
  }
  off[g] = s[t] - v;                       // exclusive within block
  if (t == 1023) btot[blockIdx.x] = s[t];  // block total
}

__global__ __launch_bounds__(512) void k_scanB(int* __restrict__ btot) {
  __shared__ int s[512];
  int t = threadIdx.x;
  int v = (t < SCAN_BLOCKS) ? btot[t] : 0;
  s[t] = v; __syncthreads();
  for (int d = 1; d < 512; d <<= 1) {
    int a = (t >= d) ? s[t - d] : 0;
    __syncthreads();
    s[t] += a;
    __syncthreads();
  }
  if (t < SCAN_BLOCKS) btot[t] = s[t] - v; // exclusive, in-place
}

__global__ __launch_bounds__(1024) void k_scanC(
    int* __restrict__ off, const int* __restrict__ btot) {
  int g = blockIdx.x * 1024 + threadIdx.x;
  off[g] += btot[blockIdx.x];
}

__global__ __launch_bounds__(256) void k_fill(
    const int* __restrict__ src, const int* __restrict__ dst,
    const int* __restrict__ ety, int* __restrict__ off,
    int* __restrict__ eidx) {
  int e = blockIdx.x * 256 + threadIdx.x;
  if (e >= E_EDGES) return;
  int key = dst[e] * 8 + ety[e];
  int p = atomicAdd(&off[key], 1);
  eidx[p] = src[e];                        // payload: source node id
}

// ---------------------------------------------------------------------------
// LDS helpers (rows padded to 136 shorts = 272B, 16B-aligned, 2-way banks).
// ---------------------------------------------------------------------------
__device__ __forceinline__ void load_w_tile(const unsigned short* __restrict__ wsrc,
                                            short (*wT)[136], int tid) {
  const uint32_t* s = (const uint32_t*)wsrc;   // bf16 [o][k], k-fast
  #pragma unroll
  for (int i = 0; i < 32; ++i) {
    int idx = tid + i * 256;          // 8192 u32
    int n = idx >> 6, kw = idx & 63;
    *(uint32_t*)&wT[n][kw * 2] = s[idx];
  }
}

// One wave computes a 16x128 output tile; A rows are wave-private
// (rows wave*16..+15). D layout: col=lane&15, row=(lane>>4)*4+i.
__device__ __forceinline__ void gemm_tile(const short (*A)[136], const short (*Bt)[136],
                                          int wave, int lane, float4v acc[8]) {
  int arow = wave * 16 + (lane & 15);
  int koff = (lane >> 4) * 8;
  #pragma unroll
  for (int kk = 0; kk < 4; ++kk) {
    short8 a = *(const short8*)&A[arow][kk * 32 + koff];
    #pragma unroll
    for (int n = 0; n < 8; ++n) {
      short8 b = *(const short8*)&Bt[n * 16 + (lane & 15)][kk * 32 + koff];
      acc[n] = __builtin_amdgcn_mfma_f32_16x16x32_bf16(a, b, acc[n], 0, 0, 0);
    }
  }
}

// ---------------------------------------------------------------------------
// K_fused: per 64-dst-node tile —
//   acc  = sum_r (edge-sum of xb[src] rows per (dst,r)) @ W_r     (rel loop)
//   acc += xb_tile @ w1 ; h1 = acc + b1 + 0                        (agg done)
//   h2 = relu(h1 @ m1 + m1b) ; out = h2 @ m2 + m2b
// No h_all / agg intermediates touch HBM.
// ---------------------------------------------------------------------------
__global__ __launch_bounds__(256, 3) void k_fused(
    const unsigned short* __restrict__ xb, const unsigned short* __restrict__ wTg,
    const int* __restrict__ off, const int* __restrict__ cnt,
    const int* __restrict__ eidx,
    const float* __restrict__ w1b, const float* __restrict__ m1b,
    const float* __restrict__ m2b, float* __restrict__ out) {
  __shared__ short xs[64][136];
  __shared__ short wT[128][136];
  int tid = threadIdx.x, wave = tid >> 6, lane = tid & 63;
  int tile0 = blockIdx.x * 64;

  float4v acc[8];
  #pragma unroll
  for (int n = 0; n < 8; ++n) acc[n] = (float4v){0.f, 0.f, 0.f, 0.f};

  // ---- relation loop: build edge-aggregated tile, MFMA vs W_r, accumulate
  for (int r = 0; r < 8; ++r) {
    // prefetch span ends/counts for my 16 rows (32 independent loads in flight)
    int e1[16], c[16];
    #pragma unroll
    for (int i = 0; i < 16; ++i) {
      int node = tile0 + wave * 16 + i;
      if (node < N_NODES) {
        int key = node * 8 + r;
        e1[i] = off[key]; c[i] = cnt[key];
      } else { e1[i] = 0; c[i] = 0; }
    }
    load_w_tile(wTg + (size_t)r * 16384, wT, tid);

    #pragma unroll 1
    for (int i = 0; i < 16; ++i) {
      int row = wave * 16 + i;
      float a0 = 0.f, a1 = 0.f;
      for (int j = e1[i] - c[i]; j < e1[i]; ++j) {
        int s = eidx[j];                                   // broadcast load
        uint32_t w = ((const uint32_t*)xb)[(size_t)s * 64 + lane];
        a0 += __uint_as_float(w << 16);
        a1 += __uint_as_float(w & 0xffff0000u);
      }
      uint32_t p = (uint32_t)f32_to_bf16(a0) | ((uint32_t)f32_to_bf16(a1) << 16);
      *(uint32_t*)&xs[row][lane * 2] = p;                  // wave-private row
    }
    __syncthreads();                  // wT staged + all xs rows written
    gemm_tile(xs, wT, wave, lane, acc);
    __syncthreads();                  // wT consumed before next r overwrites
  }

  // ---- GEMM: acc += x_tile @ w1  (then +b1 gives h1; agg already in acc)
  load_w_tile(wTg + (size_t)8 * 16384, wT, tid);
  for (int i = 0; i < 16; ++i) {                           // stage x tile (bf16)
    int idx = tid + i * 256;          // 4096 u32 over 64x128
    int row = idx >> 6, cc = idx & 63;
    int node = tile0 + row;
    uint32_t p = (node < N_NODES) ? ((const uint32_t*)xb)[(size_t)node * 64 + cc] : 0u;
    *(uint32_t*)&xs[row][cc * 2] = p;
  }
  __syncthreads();
  gemm_tile(xs, wT, wave, lane, acc);
  #pragma unroll
  for (int n = 0; n < 8; ++n)
    #pragma unroll
    for (int i = 0; i < 4; ++i) {
      int row = wave * 16 + (lane >> 4) * 4 + i;           // own rows only
      int col = n * 16 + (lane & 15);
      xs[row][col] = (short)f32_to_bf16(acc[n][i] + w1b[col]);
    }
  __syncthreads();                    // all waves done reading wT(w1)

  // ---- GEMM: h2 = relu(h1 @ m1 + m1b)
  load_w_tile(wTg + (size_t)9 * 16384, wT, tid);
  __syncthreads();
  #pragma unroll
  for (int n = 0; n < 8; ++n) acc[n] = (float4v){0.f, 0.f, 0.f, 0.f};
  gemm_tile(xs, wT, wave, lane, acc);
  #pragma unroll
  for (int n = 0; n < 8; ++n)
    #pragma unroll
    for (int i = 0; i < 4; ++i) {
      int row = wave * 16 + (lane >> 4) * 4 + i;
      int col = n * 16 + (lane & 15);
      float v = acc[n][i] + m1b[col];
      xs[row][col] = (short)f32_to_bf16(v > 0.f ? v : 0.f);
    }
  __syncthreads();

  // ---- GEMM: out = h2 @ m2 + m2b
  load_w_tile(wTg + (size_t)10 * 16384, wT, tid);
  __syncthreads();
  #pragma unroll
  for (int n = 0; n < 8; ++n) acc[n] = (float4v){0.f, 0.f, 0.f, 0.f};
  gemm_tile(xs, wT, wave, lane, acc);
  #pragma unroll
  for (int n = 0; n < 8; ++n)
    #pragma unroll
    for (int i = 0; i < 4; ++i) {
      int row = wave * 16 + (lane >> 4) * 4 + i;
      int col = n * 16 + (lane & 15);
      int node = tile0 + row;
      if (node < N_NODES) out[(size_t)node * 128 + col] = acc[n][i] + m2b[col];
    }
}

// ---------------------------------------------------------------------------
extern "C" void kernel_launch(void* const* d_in, const int* in_sizes, int n_in,
                              void* d_out, int out_size, void* d_ws, size_t ws_size,
                              hipStream_t stream) {
  const float* x     = (const float*)d_in[0];
  const int*   src   = (const int*)d_in[1];
  const int*   dst   = (const int*)d_in[2];
  const int*   ety   = (const int*)d_in[3];
  const float* W_rel = (const float*)d_in[4];
  const float* w1W   = (const float*)d_in[5];
  const float* w1b   = (const float*)d_in[6];
  const float* m1W   = (const float*)d_in[7];
  const float* m1b   = (const float*)d_in[8];
  const float* m2W   = (const float*)d_in[9];
  const float* m2b   = (const float*)d_in[10];
  float* out = (float*)d_out;

  // Workspace layout (bytes):
  char* ws = (char*)d_ws;
  unsigned short* wTg  = (unsigned short*)ws;               // 360,448 (pad 512K)
  unsigned short* xb   = (unsigned short*)(ws + 524288);    // 12,800,000
  int*            cnt  = (int*)(ws + 13324288);             // NKEYP*4 = 1,601,536
  int*            off  = (int*)(ws + 14925824);             // NKEYP*4
  int*            btot = (int*)(ws + 16527360);             // 4 KB
  int*            eidx = (int*)(ws + 16531456);             // E*4 = 2,560,000

  hipMemsetAsync(cnt, 0, (size_t)NKEYP * 4, stream);
  kx_cvt<<<6250, 256, 0, stream>>>(x, xb);
  k0_tw<<<11, 256, 0, stream>>>(W_rel, w1W, m1W, m2W, wTg);
  k_hist<<<E_EDGES / 256, 256, 0, stream>>>(dst, ety, cnt);
  k_scanA<<<SCAN_BLOCKS, 1024, 0, stream>>>(cnt, off, btot);
  k_scanB<<<1, 512, 0, stream>>>(btot);
  k_scanC<<<SCAN_BLOCKS, 1024, 0, stream>>>(off, btot);
  k_fill<<<E_EDGES / 256, 256, 0, stream>>>(src, dst, ety, off, eidx);
  k_fused<<<NB_TILES, 256, 0, stream>>>(xb, wTg, off, cnt, eidx,
                                        w1b, m1b, m2b, out);
}

// Round 6
// 365.947 us; speedup vs baseline: 1.4734x; 1.4734x over previous
//
#include <hip/hip_runtime.h>
#include <hip/hip_bf16.h>
#include <stdint.h>

// Problem constants (fixed by the reference)
#define N_NODES 50000
#define E_EDGES 640000
#define NB_TILES 782           // ceil(50000/64)
#define NKEY 400000            // N_NODES * R
#define NKEYP 400384           // 391 * 1024 (scan-padded)
#define SCAN_BLOCKS 391

typedef __attribute__((ext_vector_type(8))) short short8;   // 8 bf16 (MFMA A/B frag)
typedef __attribute__((ext_vector_type(4))) float float4v;  // MFMA C/D frag

__device__ __forceinline__ unsigned short f32_to_bf16(float f) {
  uint32_t u = __float_as_uint(f);
  u += 0x7fffu + ((u >> 16) & 1u);          // round-to-nearest-even
  return (unsigned short)(u >> 16);
}
__device__ __forceinline__ float bf16_to_f32(unsigned short h) {
  return __uint_as_float(((uint32_t)h) << 16);
}

// ---------------------------------------------------------------------------
// K_pre: fused  (a) x -> bf16 xb   [blocks 0..6249]
//               (b) weight transpose+cvt -> wTg  [blocks 6250..6260]
//               (c) histogram of key = dst*8+etype  [blocks 6261..8760]
// ---------------------------------------------------------------------------
__global__ __launch_bounds__(256) void k_pre(
    const float* __restrict__ x, const float* __restrict__ W_rel,
    const float* __restrict__ w1W, const float* __restrict__ m1W,
    const float* __restrict__ m2W, const int* __restrict__ dst,
    const int* __restrict__ ety,
    unsigned short* __restrict__ xb, unsigned short* __restrict__ wTg,
    int* __restrict__ cnt) {
  int b = blockIdx.x;
  if (b < 6250) {
    int idx = b * 256 + threadIdx.x;                 // 1.6M float4 groups
    float4 v = ((const float4*)x)[idx];
    uint32_t p0 = (uint32_t)f32_to_bf16(v.x) | ((uint32_t)f32_to_bf16(v.y) << 16);
    uint32_t p1 = (uint32_t)f32_to_bf16(v.z) | ((uint32_t)f32_to_bf16(v.w) << 16);
    ((uint2*)xb)[idx] = make_uint2(p0, p1);
  } else if (b < 6261) {
    int m = b - 6250;                                // 0..7 W_rel, 8 w1, 9 m1, 10 m2
    const float* srcp = (m < 8) ? (W_rel + (size_t)m * 16384)
                                : (m == 8 ? w1W : (m == 9 ? m1W : m2W));
    unsigned short* dstp = wTg + (size_t)m * 16384;
    for (int i = 0; i < 64; ++i) {
      int idx = threadIdx.x + i * 256;               // o*128 + k
      int o = idx >> 7, k = idx & 127;
      dstp[idx] = f32_to_bf16(srcp[k * 128 + o]);
    }
  } else {
    int e = (b - 6261) * 256 + threadIdx.x;          // 2500*256 == E exactly
    atomicAdd(&cnt[dst[e] * 8 + ety[e]], 1);
  }
}

// ---------------------------------------------------------------------------
// Exclusive scan over cnt -> off (3 kernels), then fill.
// After k_fill, off[key] == span END; span start = off[key] - cnt[key].
// ---------------------------------------------------------------------------
__global__ __launch_bounds__(1024) void k_scanA(
    const int* __restrict__ cnt, int* __restrict__ off, int* __restrict__ btot) {
  __shared__ int s[1024];
  int t = threadIdx.x, g = blockIdx.x * 1024 + t;
  int v = cnt[g];
  s[t] = v; __syncthreads();
  for (int d = 1; d < 1024; d <<= 1) {
    int a = (t >= d) ? s[t - d] : 0;
    __syncthreads();
    s[t] += a;
    __syncthreads();
  }
  off[g] = s[t] - v;
  if (t == 1023) btot[blockIdx.x] = s[t];
}

__global__ __launch_bounds__(512) void k_scanB(int* __restrict__ btot) {
  __shared__ int s[512];
  int t = threadIdx.x;
  int v = (t < SCAN_BLOCKS) ? btot[t] : 0;
  s[t] = v; __syncthreads();
  for (int d = 1; d < 512; d <<= 1) {
    int a = (t >= d) ? s[t - d] : 0;
    __syncthreads();
    s[t] += a;
    __syncthreads();
  }
  if (t < SCAN_BLOCKS) btot[t] = s[t] - v;
}

__global__ __launch_bounds__(1024) void k_scanC(
    int* __restrict__ off, const int* __restrict__ btot) {
  int g = blockIdx.x * 1024 + threadIdx.x;
  off[g] += btot[blockIdx.x];
}

__global__ __launch_bounds__(256) void k_fill(
    const int* __restrict__ src, const int* __restrict__ dst,
    const int* __restrict__ ety, int* __restrict__ off,
    int* __restrict__ eidx) {
  int e = blockIdx.x * 256 + threadIdx.x;
  if (e >= E_EDGES) return;
  int key = dst[e] * 8 + ety[e];
  int p = atomicAdd(&off[key], 1);
  eidx[p] = src[e];
}

// ---------------------------------------------------------------------------
// gemm_tile_g: one wave computes a 16x128 tile; A from LDS (wave-private
// rows), B read DIRECTLY from global wTg (L2-resident; per load the wave
// touches 16 rows x one 64B line). D layout: col=lane&15, row=(lane>>4)*4+i.
// ---------------------------------------------------------------------------
__device__ __forceinline__ void gemm_tile_g(const short (*A)[136],
    const unsigned short* __restrict__ Bt, int wave, int lane, float4v acc[8]) {
  int arow = wave * 16 + (lane & 15);
  int koff = (lane >> 4) * 8;
  #pragma unroll
  for (int kk = 0; kk < 4; ++kk) {
    short8 a = *(const short8*)&A[arow][kk * 32 + koff];
    #pragma unroll
    for (int n = 0; n < 8; ++n) {
      short8 b = *(const short8*)&Bt[(size_t)(n * 16 + (lane & 15)) * 128 + kk * 32 + koff];
      acc[n] = __builtin_amdgcn_mfma_f32_16x16x32_bf16(a, b, acc[n], 0, 0, 0);
    }
  }
}

// ---------------------------------------------------------------------------
// K_fused (barrier-free): per 64-dst-node tile, per wave (16 rows):
//   rel loop: quarter-wave edge-gather (4 concurrent chains) -> xs rows,
//             MFMA vs W_r from global, accumulate
//   then acc += x@w1 ; h1=acc+b1 ; h2=relu(h1@m1+m1b) ; out=h2@m2+m2b.
// xs rows are wave-private => zero __syncthreads in the whole kernel.
// ---------------------------------------------------------------------------
__global__ __launch_bounds__(256, 4) void k_fused(
    const unsigned short* __restrict__ xb, const unsigned short* __restrict__ wTg,
    const int* __restrict__ off, const int* __restrict__ cnt,
    const int* __restrict__ eidx,
    const float* __restrict__ w1b, const float* __restrict__ m1b,
    const float* __restrict__ m2b, float* __restrict__ out) {
  __shared__ short xs[64][136];          // 17.4 KB, rows wave-private
  int tid = threadIdx.x, wave = tid >> 6, lane = tid & 63;
  int q = lane >> 4, l16 = lane & 15;    // quarter-wave id / lane-in-quarter
  int tile0 = blockIdx.x * 64;

  float4v acc[8];
  #pragma unroll
  for (int n = 0; n < 8; ++n) acc[n] = (float4v){0.f, 0.f, 0.f, 0.f};

  // ---- relation loop -------------------------------------------------
  for (int r = 0; r < 8; ++r) {
    // quarter-wave q aggregates rows q*4..q*4+3; 4 independent chains/wave.
    // Padded nodes (>=N) have cnt==0 spans (cnt memset covers NKEYP), so no guard.
    #pragma unroll
    for (int ri = 0; ri < 4; ++ri) {
      int i = q * 4 + ri;
      int row = wave * 16 + i;
      int key = (tile0 + row) * 8 + r;
      int e1 = off[key], cv = cnt[key];
      float a[8];
      #pragma unroll
      for (int k = 0; k < 8; ++k) a[k] = 0.f;
      int j0 = e1 - cv;
      int sN = (cv > 0) ? eidx[j0] : 0;            // prefetch first src id
      for (int j = j0; j < e1; ++j) {
        int s = sN;
        if (j + 1 < e1) sN = eidx[j + 1];          // one-ahead prefetch
        short8 w = *(const short8*)&xb[(size_t)s * 128 + l16 * 8];
        #pragma unroll
        for (int k = 0; k < 8; ++k) a[k] += bf16_to_f32((unsigned short)w[k]);
      }
      uint32_t p0 = (uint32_t)f32_to_bf16(a[0]) | ((uint32_t)f32_to_bf16(a[1]) << 16);
      uint32_t p1 = (uint32_t)f32_to_bf16(a[2]) | ((uint32_t)f32_to_bf16(a[3]) << 16);
      uint32_t p2 = (uint32_t)f32_to_bf16(a[4]) | ((uint32_t)f32_to_bf16(a[5]) << 16);
      uint32_t p3 = (uint32_t)f32_to_bf16(a[6]) | ((uint32_t)f32_to_bf16(a[7]) << 16);
      *(uint4*)&xs[row][l16 * 8] = make_uint4(p0, p1, p2, p3);
    }
    // same-wave LDS write->read: compiler inserts lgkmcnt wait; no barrier.
    gemm_tile_g(xs, wTg + (size_t)r * 16384, wave, lane, acc);
  }

  // ---- acc += x_tile @ w1 --------------------------------------------
  #pragma unroll
  for (int i = 0; i < 16; ++i) {
    int row = wave * 16 + i;
    int node = tile0 + row;
    uint32_t pv = (node < N_NODES) ? ((const uint32_t*)xb)[(size_t)node * 64 + lane] : 0u;
    *(uint32_t*)&xs[row][lane * 2] = pv;
  }
  gemm_tile_g(xs, wTg + (size_t)8 * 16384, wave, lane, acc);

  // h1 = acc + w1b  -> xs (bf16)   [agg already accumulated in acc]
  #pragma unroll
  for (int n = 0; n < 8; ++n)
    #pragma unroll
    for (int i = 0; i < 4; ++i) {
      int row = wave * 16 + (lane >> 4) * 4 + i;
      int col = n * 16 + (lane & 15);
      xs[row][col] = (short)f32_to_bf16(acc[n][i] + w1b[col]);
    }

  // ---- h2 = relu(h1 @ m1 + m1b) --------------------------------------
  #pragma unroll
  for (int n = 0; n < 8; ++n) acc[n] = (float4v){0.f, 0.f, 0.f, 0.f};
  gemm_tile_g(xs, wTg + (size_t)9 * 16384, wave, lane, acc);
  #pragma unroll
  for (int n = 0; n < 8; ++n)
    #pragma unroll
    for (int i = 0; i < 4; ++i) {
      int row = wave * 16 + (lane >> 4) * 4 + i;
      int col = n * 16 + (lane & 15);
      float v = acc[n][i] + m1b[col];
      xs[row][col] = (short)f32_to_bf16(v > 0.f ? v : 0.f);
    }

  // ---- out = h2 @ m2 + m2b -------------------------------------------
  #pragma unroll
  for (int n = 0; n < 8; ++n) acc[n] = (float4v){0.f, 0.f, 0.f, 0.f};
  gemm_tile_g(xs, wTg + (size_t)10 * 16384, wave, lane, acc);
  #pragma unroll
  for (int n = 0; n < 8; ++n)
    #pragma unroll
    for (int i = 0; i < 4; ++i) {
      int row = wave * 16 + (lane >> 4) * 4 + i;
      int col = n * 16 + (lane & 15);
      int node = tile0 + row;
      if (node < N_NODES) out[(size_t)node * 128 + col] = acc[n][i] + m2b[col];
    }
}

// ---------------------------------------------------------------------------
extern "C" void kernel_launch(void* const* d_in, const int* in_sizes, int n_in,
                              void* d_out, int out_size, void* d_ws, size_t ws_size,
                              hipStream_t stream) {
  const float* x     = (const float*)d_in[0];
  const int*   src   = (const int*)d_in[1];
  const int*   dst   = (const int*)d_in[2];
  const int*   ety   = (const int*)d_in[3];
  const float* W_rel = (const float*)d_in[4];
  const float* w1W   = (const float*)d_in[5];
  const float* w1b   = (const float*)d_in[6];
  const float* m1W   = (const float*)d_in[7];
  const float* m1b   = (const float*)d_in[8];
  const float* m2W   = (const float*)d_in[9];
  const float* m2b   = (const float*)d_in[10];
  float* out = (float*)d_out;

  // Workspace layout (bytes):
  char* ws = (char*)d_ws;
  unsigned short* wTg  = (unsigned short*)ws;               // 360,448 (pad 512K)
  unsigned short* xb   = (unsigned short*)(ws + 524288);    // 12,800,000
  int*            cnt  = (int*)(ws + 13324288);             // NKEYP*4
  int*            off  = (int*)(ws + 14925824);             // NKEYP*4
  int*            btot = (int*)(ws + 16527360);             // 4 KB
  int*            eidx = (int*)(ws + 16531456);             // E*4

  hipMemsetAsync(cnt, 0, (size_t)NKEYP * 4, stream);
  k_pre<<<8761, 256, 0, stream>>>(x, W_rel, w1W, m1W, m2W, dst, ety, xb, wTg, cnt);
  k_scanA<<<SCAN_BLOCKS, 1024, 0, stream>>>(cnt, off, btot);
  k_scanB<<<1, 512, 0, stream>>>(btot);
  k_scanC<<<SCAN_BLOCKS, 1024, 0, stream>>>(off, btot);
  k_fill<<<E_EDGES / 256, 256, 0, stream>>>(src, dst, ety, off, eidx);
  k_fused<<<NB_TILES, 256, 0, stream>>>(xb, wTg, off, cnt, eidx,
                                        w1b, m1b, m2b, out);
}